// Round 11
// baseline (23260.442 us; speedup 1.0000x reference)
//
#include <hip/hip_runtime.h>
#include <math.h>

// ws layout (floats)
#define H0A_OFF  0            // [64][512] h0, step parity 0
#define H0B_OFF  32768        // [64][512] h0, step parity 1
#define H1_OFF   65536        // [64][512] h1
#define RH0_OFF  98304        // [64][512]
#define RH1_OFF  131072       // [64][512]
#define FLG_OFF  163840       // u32: rhF[4 dom][64] then hF[4 dom][64]
#define WS_FLOATS (163840 + 1024)
#define WS_BYTES  (WS_FLOATS * 4)

// LDS row stride (words). 516 % 32 == 4: rows rgl=0..7 -> 8 distinct bank
// quads -> conflict-free b128 state reads. 516 % 4 == 0 keeps 16B alignment.
#define SROW 516

__device__ __forceinline__ void gstore(float* p, float v) {
    __hip_atomic_store(p, v, __ATOMIC_RELAXED, __HIP_MEMORY_SCOPE_AGENT);
}
__device__ __forceinline__ unsigned gloadU(const unsigned* p) {
    return __hip_atomic_load(p, __ATOMIC_RELAXED, __HIP_MEMORY_SCOPE_AGENT);
}
__device__ __forceinline__ void gstoreU(unsigned* p, unsigned v) {
    __hip_atomic_store(p, v, __ATOMIC_RELAXED, __HIP_MEMORY_SCOPE_AGENT);
}
__device__ __forceinline__ float fma4(float4 w, float4 x, float a) {
    a = fmaf(w.x, x.x, a); a = fmaf(w.y, x.y, a);
    a = fmaf(w.z, x.z, a); a = fmaf(w.w, x.w, a);
    return a;
}

// Per-wave 64-col slice (32 rows x 64 cols, 8 KB) of a [32][512] global
// region: issue 8 coherent b128 loads. NOT valid until a vmcnt drain.
__device__ __forceinline__ void issueSlice(float4 t[8], const float* __restrict__ src,
                                           int lane, int cbase) {
    #pragma unroll
    for (int i = 0; i < 8; ++i) {
        int f4i = lane + 64 * i, rowL = f4i >> 4, c4 = f4i & 15;
        const float* p = src + rowL * 512 + cbase + 4 * c4;
        asm volatile("global_load_dwordx4 %0, %1, off sc0 sc1"
                     : "=&v"(t[i]) : "v"(p) : "memory");
    }
}
__device__ __forceinline__ void writeSlice(float* __restrict__ buf, const float4 t[8],
                                           int lane, int cbase) {
    #pragma unroll
    for (int i = 0; i < 8; ++i) {
        int f4i = lane + 64 * i, rowL = f4i >> 4, c4 = f4i & 15;
        *(float4*)&buf[rowL * SROW + cbase + 4 * c4] = t[i];
    }
}
__device__ __forceinline__ void drain_all() {
    asm volatile("s_waitcnt vmcnt(0)" ::: "memory");
}
// Wait until at most the 8 NEWEST vmem ops of THIS WAVE remain outstanding
// (FIFO): completes everything issued before them.
__device__ __forceinline__ void drain_keep8() {
    asm volatile("s_waitcnt vmcnt(8)" ::: "memory");
}

// Per-wave producer-group wait: lanes 0-7 poll F[base+lane] >= tgt, skipping
// index==skip (own block: covered by program order + sync drains). Flags are
// monotonic, stored AFTER a __syncthreads that drained the producer's data
// stores (HIP barrier semantics) -> flag>=tgt implies data visible at agent
// coherence for sc0/sc1 loads.
__device__ __forceinline__ void wait8(const unsigned* F, int base, int skip,
                                      unsigned tgt, int lane) {
    for (;;) {
        bool ok = true;
        if (lane < 8) {
            int jj = base + lane;
            ok = (jj == skip) || ((int)(gloadU(F + jj) - tgt) >= 0);
        }
        if (__ballot(ok) == ~0ull) break;
        __builtin_amdgcn_s_sleep(2);
    }
}

__global__ __launch_bounds__(512, 1) void gru_main(
    const int* __restrict__ tokens, const float* __restrict__ emb,
    const float* __restrict__ Wr0, const float* __restrict__ br0,
    const float* __restrict__ Wz0, const float* __restrict__ bz0,
    const float* __restrict__ Wh0, const float* __restrict__ bh0,
    const float* __restrict__ Wr1, const float* __restrict__ br1,
    const float* __restrict__ Wz1, const float* __restrict__ bz1,
    const float* __restrict__ Wh1, const float* __restrict__ bh1,
    float* __restrict__ ws)
{
    const int blk = blockIdx.x;
    const int tid = threadIdx.x;

    // XCD = blk%8 = rg*4 + jl -> per-XCD weight footprint L2-resident.
    const int rg    = (blk >> 2) & 1;
    const int jl    = blk & 3;
    const int jh    = (blk >> 3) & 15;
    const int layer = blk >> 7;
    const int j     = jh * 4 + jl;
    const int ks    = tid >> 6;           // 8 waves, wave = k-slice (R10 mapping)
    const int lane  = tid & 63;
    const int c     = lane >> 3;
    const int rgl   = lane & 7;
    const int rowbase = rg * 32;
    const int cg    = j * 8 + c;
    const int cR    = (tid >> 5) & 7;     // reducer col (tid<256 only)
    const int riR   = tid & 31;           // reducer row
    const int cgR   = j * 8 + cR;

    // Producer-group flag arrays. dom = layer*2 + rg.
    // rhF[dom][jj] = s+1  <=> block jj of dom finished R1(s) (rh[s] visible).
    // hF[dom][jj]  = s+1  <=> block jj of dom finished R2(s) (h[s] visible).
    unsigned* flg  = (unsigned*)(ws + FLG_OFF);
    const int dom  = layer * 2 + rg;
    unsigned* rhF  = flg;
    unsigned* hF   = flg + 256;
    unsigned* rhFd = rhF + dom * 64;           // own domain
    unsigned* hFd  = hF + dom * 64;
    unsigned* hFx  = hF + rg * 64;             // L0 domain, same rg (L1 x poll)
    unsigned* rhFo = rhF + (2 + rg) * 64;      // L1 domain, same rg (L0 gate)

    const int S1 = layer ? 512 : 256;
    const int K  = S1 + 512;
    const float* WrL = layer ? Wr1 : Wr0;
    const float* WzL = layer ? Wz1 : Wz0;
    const float* WhL = layer ? Wh1 : Wh0;
    const float* wrRow = WrL + (size_t)cg * K;
    const float* wzRow = WzL + (size_t)cg * K;
    const float* whRow = WhL + (size_t)cg * K;
    const float bR = (layer ? br1 : br0)[cgR];
    const float bZ = (layer ? bz1 : bz0)[cgR];
    const float bH = (layer ? bh1 : bh0)[cgR];

    // h0 double-buffered by step parity (anti-clobber via the all-64 L1 gate
    // at L0's R2). h1 and rh single-buffered: safe because each block's
    // pre-R1/pre-R2 __syncthreads couples its 8 waves, whose producer polls
    // transitively imply all 64 domain blocks passed the prior phase.
    const float* h0buf[2] = { ws + H0A_OFF, ws + H0B_OFF };
    float* h0bufW[2] = { ws + H0A_OFF, ws + H0B_OFF };
    float* h1p   = ws + H1_OFF;
    float* rhOwn = ws + (layer ? RH1_OFF : RH0_OFF);

    // bufA = x (wave-private col slices); bufB = h_prev -> rh (wave-private;
    // only cross-wave read is R1's hp, behind sync#1).
    __shared__ float bufA[32 * SROW];    // 66,048 B
    __shared__ float bufB[32 * SROW];    // 66,048 B
    __shared__ float pTmp[3 * 2048];     // 24,576 B   total 156,672 B

    const int k1     = ks * (S1 >> 3);    // seg1 wave col base (L0:32w, L1:64w)
    const int k2s    = ks * 64;           // seg2/D3 wave col base (state)
    const int k2base = S1 + k2s;          // seg2/D3 weight col base
    const int nq1    = S1 >> 5;           // seg1 f4-iters (L0:8, L1:16)

    for (int s = 0; s <= 1024; ++s) {
        const bool act = layer ? (s >= 1) : (s < 1024);
        float zv = 0.f, hp = 0.f, hx = 0.f;
        float aR[4] = {0,0,0,0}, aZ[4] = {0,0,0,0}, aH[4] = {0,0,0,0};

        // ---- phase A (wave-private): poll producers, stage x slice
        //      (drained) + h_prev slice (left in flight under seg1 dot). ----
        if (act) {
            float4 thp[8];
            if (layer) {
                float4 tx[8];
                wait8(hFx, 8 * ks, -1, (unsigned)s, lane);      // x prod (L0, h0[s-1])
                issueSlice(tx, h0buf[(s - 1) & 1] + rowbase * 512, lane, k1);
                wait8(hFd, 8 * ks, j, (unsigned)s, lane);       // h1[s-1] producers
                issueSlice(thp, h1p + rowbase * 512, lane, k2s);
                drain_keep8();                             // x done, thp in flight
                writeSlice(bufA, tx, lane, k1);
            } else {
                float4 tx[4];
                wait8(hFd, 8 * ks, j, (unsigned)s, lane);       // h0[s-1] producers
                #pragma unroll
                for (int i = 0; i < 4; ++i) {              // emb gather (32x32 slice)
                    int f4i = lane + 64 * i, rowL = f4i >> 3, c4 = f4i & 7;
                    int tok = tokens[(rowbase + rowL) * 1024 + s];
                    tx[i] = *(const float4*)(emb + (size_t)tok * 256 + k1 + 4 * c4);
                }
                issueSlice(thp, h0buf[(s - 1) & 1] + rowbase * 512, lane, k2s);
                drain_keep8();                             // emb done, thp in flight
                #pragma unroll
                for (int i = 0; i < 4; ++i) {
                    int f4i = lane + 64 * i, rowL = f4i >> 3, c4 = f4i & 7;
                    *(float4*)&bufA[rowL * SROW + k1 + 4 * c4] = tx[i];
                }
            }

            // ---- seg1 dot: x slice in bufA; weights stream from L2;
            //      h_prev loads still in flight ----
            #pragma unroll 4
            for (int i = 0; i < nq1; ++i) {
                int kk = k1 + 4 * i;
                float4 w1 = *(const float4*)(wrRow + kk);
                float4 w2 = *(const float4*)(wzRow + kk);
                float4 w3 = *(const float4*)(whRow + kk);
                #pragma unroll
                for (int rr = 0; rr < 4; ++rr) {
                    float4 xv = *(const float4*)(&bufA[(rgl + 8 * rr) * SROW + kk]);
                    aR[rr] = fma4(w1, xv, aR[rr]);
                    aZ[rr] = fma4(w2, xv, aZ[rr]);
                    aH[rr] = fma4(w3, xv, aH[rr]);
                }
            }

            drain_all();                                   // h_prev slice arrived
            writeSlice(bufB, thp, lane, k2s);

            // ---- seg2: r,z recurrent dot (weights from L2, verified order) ----
            #pragma unroll 4
            for (int i = 0; i < 16; ++i) {
                int kw  = k2base + 4 * i;
                int kst = k2s + 4 * i;
                float4 w1 = *(const float4*)(wrRow + kw);
                float4 w2 = *(const float4*)(wzRow + kw);
                #pragma unroll
                for (int rr = 0; rr < 4; ++rr) {
                    float4 xv = *(const float4*)(&bufB[(rgl + 8 * rr) * SROW + kst]);
                    aR[rr] = fma4(w1, xv, aR[rr]);
                    aZ[rr] = fma4(w2, xv, aZ[rr]);
                }
            }
            #pragma unroll
            for (int rr = 0; rr < 4; ++rr) {
                int o = ks * 256 + c * 32 + (rgl + 8 * rr);
                pTmp[o]        = aR[rr];
                pTmp[2048 + o] = aZ[rr];
                pTmp[4096 + o] = aH[rr];
            }
        }
        __syncthreads();                                   // #1

        // ---- R1: reduce + activations + publish rh ----
        if (act && tid < 256) {
            int o = cR * 32 + riR;
            float sR = 0.f, sZ = 0.f, sH = 0.f;
            #pragma unroll
            for (int p = 0; p < 8; ++p) {
                sR += pTmp[o + 256 * p];
                sZ += pTmp[2048 + o + 256 * p];
                sH += pTmp[4096 + o + 256 * p];
            }
            float rv = 1.f / (1.f + expf(-(sR + bR)));
            zv = 1.f / (1.f + expf(-(sZ + bZ)));
            hx = sH;
            hp = bufB[riR * SROW + cgR];          // bufB holds h_prev
            gstore(rhOwn + (rowbase + riR) * 512 + cgR, rv * hp);
        }
        __syncthreads();                                   // #2 (drains R1 stores)
        if (tid == 0) gstoreU(rhFd + j, (unsigned)(s + 1));

        // ---- P2 (wave-private): poll rh producers, stage rh slice, D3 dot ----
        if (act) {
            float4 trh[8];
            wait8(rhFd, 8 * ks, j, (unsigned)(s + 1), lane);
            issueSlice(trh, rhOwn + rowbase * 512, lane, k2s);
            drain_all();
            writeSlice(bufB, trh, lane, k2s);
            float a3[4] = {0,0,0,0};
            #pragma unroll 4
            for (int i = 0; i < 16; ++i) {
                int kw  = k2base + 4 * i;
                int kst = k2s + 4 * i;
                float4 w3 = *(const float4*)(whRow + kw);
                #pragma unroll
                for (int rr = 0; rr < 4; ++rr) {
                    float4 xv = *(const float4*)(&bufB[(rgl + 8 * rr) * SROW + kst]);
                    a3[rr] = fma4(w3, xv, a3[rr]);
                }
            }
            #pragma unroll
            for (int rr = 0; rr < 4; ++rr)
                pTmp[ks * 256 + c * 32 + (rgl + 8 * rr)] = a3[rr];
        }
        __syncthreads();                                   // #3

        // ---- R2: reduce + tanh + publish h[s] ----
        if (act && tid < 256) {
            if (!layer && s >= 2) {
                // h0 parity anti-clobber: all 64 L1(rg) blocks past R1(s-1)
                // (rhF >= s) => their phase-A x-reads of h0[s-2] are done.
                // 2-step slack: normally pre-satisfied, one coalesced round.
                for (;;) {
                    bool ok = ((int)(gloadU(rhFo + lane) - (unsigned)s) >= 0);
                    if (__ballot(ok) == ~0ull) break;
                    __builtin_amdgcn_s_sleep(2);
                }
            }
            float* hWriteP = layer ? h1p : h0bufW[s & 1];
            int o = cR * 32 + riR;
            float sH2 = 0.f;
            #pragma unroll
            for (int p = 0; p < 8; ++p) sH2 += pTmp[o + 256 * p];
            float ht = tanhf(hx + sH2 + bH);
            float hn = (1.f - zv) * hp + zv * ht;
            gstore(hWriteP + (rowbase + riR) * 512 + cgR, hn);
        }
        __syncthreads();                                   // #4 (drains R2 stores)
        if (tid == 0) gstoreU(hFd + j, (unsigned)(s + 1));
    }
}

__global__ __launch_bounds__(128) void gru_fc(
    const float* __restrict__ h1f, const float* __restrict__ fcW,
    const float* __restrict__ fcb, float* __restrict__ out)
{
    int tid = threadIdx.x;
    int b = tid >> 1, cc = tid & 1;
    const float* hrow = h1f + b * 512;
    const float* wrow = fcW + cc * 512;
    float acc = 0.f;
    #pragma unroll 4
    for (int k = 0; k < 512; k += 4) {
        float4 hv = *(const float4*)(hrow + k);
        float4 wv = *(const float4*)(wrow + k);
        acc = fmaf(hv.x, wv.x, fmaf(hv.y, wv.y, fmaf(hv.z, wv.z, fmaf(hv.w, wv.w, acc))));
    }
    out[b * 2 + cc] = acc + fcb[cc];
}

extern "C" void kernel_launch(void* const* d_in, const int* in_sizes, int n_in,
                              void* d_out, int out_size, void* d_ws, size_t ws_size,
                              hipStream_t stream) {
    const int* tokens = (const int*)d_in[0];
    const float* emb = (const float*)d_in[1];
    const float* Wr0 = (const float*)d_in[2];  const float* br0 = (const float*)d_in[3];
    const float* Wz0 = (const float*)d_in[4];  const float* bz0 = (const float*)d_in[5];
    const float* Wh0 = (const float*)d_in[6];  const float* bh0 = (const float*)d_in[7];
    const float* Wr1 = (const float*)d_in[8];  const float* br1 = (const float*)d_in[9];
    const float* Wz1 = (const float*)d_in[10]; const float* bz1 = (const float*)d_in[11];
    const float* Wh1 = (const float*)d_in[12]; const float* bh1 = (const float*)d_in[13];
    const float* fcW = (const float*)d_in[14]; const float* fcb = (const float*)d_in[15];
    float* ws = (float*)d_ws;

    hipMemsetAsync(d_ws, 0, WS_BYTES, stream);

    gru_main<<<256, 512, 0, stream>>>(tokens, emb, Wr0, br0, Wz0, bz0, Wh0, bh0,
                                      Wr1, br1, Wz1, bz1, Wh1, bh1, ws);
    gru_fc<<<1, 128, 0, stream>>>(ws + H1_OFF, fcW, fcb, (float*)d_out);
}